// Round 9
// baseline (165.468 us; speedup 1.0000x reference)
//
#include <hip/hip_runtime.h>
#include <float.h>

// Problem constants (fixed by reference: B=8, D=64, H=64, W=64, K=8192)
constexpr int KCODES = 8192;
constexpr int DDIM   = 64;
constexpr int NTOK   = 32768;
constexpr int MT     = 128;                // tokens per WG (2 halves x 4 sets x 16)
constexpr int NSETS  = 4;                  // sets per wave (64 tokens)
constexpr int KC     = 64;                 // codes per chunk
constexpr int NCH    = KCODES / KC;        // 128 chunks
constexpr int CBCHUNK = KC * DDIM * 2;     // 8192 B (64 codes x 64 d x bf16, hi only)

constexpr int RB    = 3;                   // shared staging ring depth (per WG)
constexpr int BUFB  = 8192;                // ring buffer bytes (one chunk)
constexpr int HNOFF = RB * BUFB;           // 24576: hn block base in LDS
constexpr int NCELL = 16;                  // per token-half: 4 wr x 4 quads

typedef short v8s __attribute__((ext_vector_type(8)));
typedef float v4f __attribute__((ext_vector_type(4)));

static __device__ __forceinline__ unsigned short f2bf(float f) {
  union { float f; unsigned u; } v; v.f = f;
  return (unsigned short)((v.u + 0x7fffu + ((v.u >> 16) & 1u)) >> 16);  // RNE
}

// async global->LDS DMA: dest = wave-uniform LDS base + lane*16 (m104);
// source is per-lane. Tracked by vmcnt.
static __device__ __forceinline__ void dma16(const void* g, void* l) {
  __builtin_amdgcn_global_load_lds(
      (const __attribute__((address_space(1))) void*)g,
      (__attribute__((address_space(3))) void*)l, 16, 0, 0);
}

// ---- fused prep: bf16 hi codebook, FRAGMENT-LINEAR for mfma_16x16x32_bf16
// A-operand (A[m=lane&15][k=(lane>>4)*8+j]), + biased half-norms
// hn[k] = 0.5*||c_k||^2 + 2.0 (bias keeps phase-1 scores positive -> fp32
// bit pattern monotone for the packed-key argmin; scores land in [~0.7,~4.5]).
// Per chunk c: byte off = c*8192 + g*2048 + ks*1024 + lane*16 + j*2.
// Grid 256 x 128 threads (2 blocks per chunk): full-device fill.
__global__ __launch_bounds__(128) void prep_kernel(
    const float* __restrict__ cb, unsigned short* __restrict__ wcb,
    float* __restrict__ hn) {
  const int c = blockIdx.x >> 1;            // chunk 0..127
  const int tid = threadIdx.x;
  const int g = ((blockIdx.x & 1) << 1) | (tid >> 6);   // 16-code group 0..3
  const int lane = tid & 63;
  const int quad = lane >> 4, col = lane & 15;
  const int code = c * KC + g * 16 + col;
  const float* src = cb + (size_t)code * DDIM;
  float sq = 0.f;
#pragma unroll
  for (int ks = 0; ks < 2; ++ks) {
    v8s hi;
#pragma unroll
    for (int j = 0; j < 8; ++j) {
      const float x = src[ks * 32 + quad * 8 + j];
      sq += x * x;
      hi[j] = (short)f2bf(x);
    }
    const size_t b0 = ((size_t)c * CBCHUNK + g * 2048 + ks * 1024 + lane * 16) / 2;
    *reinterpret_cast<v8s*>(wcb + b0) = hi;
  }
  sq += __shfl_xor(sq, 16);
  sq += __shfl_xor(sq, 32);
  if (quad == 0) hn[code] = 0.5f * sq + 2.0f;
}

// Phase 1 (SCREEN): hi-only bf16 MFMA, score ~= hn - xh.ch.
//   Screening error e = xl.c + xh.cl: RMS ~2.5e-4, |e| <= ~2.8e-3 at 11
//   sigma. 512-thread WG, MT=128 tokens, WG-SHARED staging: each chunk's
//   8 KB is staged ONCE per WG into a shared 3-deep LDS ring (each wave
//   issues exactly 1 dma16 = its wv*1024 slice) and consumed by all 8
//   waves (waves 0-3 = tokens 0..63, waves 4-7 = tokens 64..127; code
//   row-slice wr = wv&3). Per-CU codebook traffic HALVES vs the per-wave
//   ring at MT=64 (1.05 MB vs 2.1 MB) at the same 8 waves/CU TLP and the
//   same 1024 wave-chunks/CU — isolates bytes-bound vs overhead-bound.
//   2-phase schedule per chunk with counted vmcnt (uniform 1 op/stage):
//   { s_waitcnt vmcnt(2) [my chunk-it slice landed; it+1,it+2 in flight],
//     s_barrier [all slices landed], ds_read A+hv, lgkmcnt(0),
//     s_barrier [all reads done -> buf safe], stage(it+3 -> same buf) }.
//   Tail wrap (&127) restages chunks 0..2: redundant, never read, drained
//   by vmcnt(0)+syncthreads before the epilogue aliases the ring. hn
//   staged ONCE into LDS (32 KB) so the loop's vmcnt domain contains
//   ONLY the 1-per-stage DMAs. Branchless packed-key top-2 per
//   (lane,set) cell: key = (score-bits & ~511) | (it*4 + r), it<128 so
//   the 9-bit field holds; floor quantization <= 512 ulp <= 2.4e-4.
// Phase 2: fast path when unique candidate within smin+8e-3. Proof: for any
//   candidate with stored > lim: true > stored - e > smin + 8e-3 - 2.8e-3;
//   smin >= true_min - e - 2.4e-4 -> true - true_min > 8e-3 - 5.6e-3 -
//   2.4e-4 > 2e-3 >> numpy's ulp(64) ~1.5e-5 quantization -> numpy cannot
//   prefer it. A numpy-winner distinct from the approx winner is itself
//   within lim -> cnt >= 2 -> refine. Refine = numpy-fp32-faithful decision
//   (pairwise-8 sums, D=fl(fl(S-2p)+N), correctly-rounded-fp64 p,
//   tie -> lowest index) — identical to all passing rounds. (Each token
//   sees 16 cells x 512 codes, same partition structure as R3.)
__global__ __launch_bounds__(512) void vq_kernel(
    const float* __restrict__ ze, const float* __restrict__ cb,
    const float* __restrict__ hn, const unsigned short* __restrict__ wcb,
    float* __restrict__ out) {
  // LDS map: [0, 24576) shared 3-deep chunk ring; [24576, 57344) hn copy.
  // Epilogue arrays (33 KB) alias the ring after drain + syncthreads.
  __shared__ __align__(16) char smem[57344];

  const int tid = threadIdx.x, lane = tid & 63, wv = tid >> 6;
  const int col = lane & 15, quad = lane >> 4;
  const int wr = wv & 3;              // code row-slice (16 codes of each chunk)
  const int tg = wv >> 2;             // token half 0/1
  const int t0 = blockIdx.x * MT;
  const int bb = t0 >> 12, hw0 = t0 & 4095;   // 4096 % 128 == 0: one batch per WG
  const float* zb = ze + (size_t)bb * (DDIM * 4096) + hw0;

  // ---- one-time hn -> LDS copy (32 KB, 4 x float4 per thread) ----
  {
    v4f* dst = (v4f*)(smem + HNOFF);
    const v4f* src = (const v4f*)hn;
#pragma unroll
    for (int i = 0; i < 4; ++i) dst[tid + i * 512] = src[tid + i * 512];
  }

  // ---- B-frags: 4 sets x 16 tokens of this wave's token-half, negated
  // bf16-hi, in registers. token = tg*64 + s*16 + col; d = ks*32 + quad*8 + j.
  v8s nxh[NSETS][2];
#pragma unroll
  for (int s = 0; s < NSETS; ++s) {
    const int mtok = tg * 64 + s * 16 + col;
#pragma unroll
    for (int ks = 0; ks < 2; ++ks) {
#pragma unroll
      for (int j = 0; j < 8; ++j) {
        const int d = ks * 32 + quad * 8 + j;
        nxh[s][ks][j] = (short)f2bf(-zb[(size_t)d * 4096 + mtok]);
      }
    }
  }

  // Stage chunk -> ring buf: this wave's 1 KB slice (slice wv of 8).
  auto stage = [&](int chunk, int buf) {
    const char* src = (const char*)wcb + (size_t)chunk * CBCHUNK + wv * 1024 + lane * 16;
    char* dst = smem + buf * BUFB + wv * 1024 + lane * 16;
    dma16(src, dst);
  };

  unsigned m1[NSETS] = {0xFFFFFFFFu, 0xFFFFFFFFu, 0xFFFFFFFFu, 0xFFFFFFFFu};
  unsigned m2[NSETS] = {0xFFFFFFFFu, 0xFFFFFFFFu, 0xFFFFFFFFu, 0xFFFFFFFFu};

  auto compute = [&](const v8s (&A)[2], const v4f hv, int it) {
    const unsigned base9 = (unsigned)(it * 4);   // 9-bit cell-local index base
#pragma unroll
    for (int s = 0; s < NSETS; ++s) {            // 4 independent MFMA chains
      v4f acc = __builtin_amdgcn_mfma_f32_16x16x32_bf16(A[0], nxh[s][0], hv, 0, 0, 0);
      acc = __builtin_amdgcn_mfma_f32_16x16x32_bf16(A[1], nxh[s][1], acc, 0, 0, 0);
      unsigned k0 = (__float_as_uint(acc[0]) & ~511u) | (base9 + 0);
      unsigned k1 = (__float_as_uint(acc[1]) & ~511u) | (base9 + 1);
      unsigned k2 = (__float_as_uint(acc[2]) & ~511u) | (base9 + 2);
      unsigned k3 = (__float_as_uint(acc[3]) & ~511u) | (base9 + 3);
      const unsigned km = min(min(k0, k1), min(k2, k3));
      const unsigned old1 = m1[s];
      m1[s] = min(old1, km);
      m2[s] = min(m2[s], max(old1, km));   // branchless 2nd-best
    }
  };

  // hn LDS writes + prologue global loads fully drained & visible.
  __syncthreads();
  asm volatile("s_waitcnt vmcnt(0)" ::: "memory");
  __builtin_amdgcn_sched_barrier(0);

#pragma unroll
  for (int r = 0; r < RB; ++r) stage(r, r);   // 3 slices in flight per wave

  int bf = 0;
  for (int it = 0; it < NCH; ++it) {
    // My slice of chunk `it` landed once <= 2 of my ops remain outstanding.
    asm volatile("s_waitcnt vmcnt(2)" ::: "memory");
    __builtin_amdgcn_sched_barrier(0);
    __builtin_amdgcn_s_barrier();              // all 8 slices of chunk it landed
    __builtin_amdgcn_sched_barrier(0);

    v8s A[2]; v4f hv;
    {
      const char* b = smem + bf * BUFB + wr * 2048;
      A[0] = *reinterpret_cast<const v8s*>(b + lane * 16);
      A[1] = *reinterpret_cast<const v8s*>(b + 1024 + lane * 16);
      hv   = *reinterpret_cast<const v4f*>(smem + HNOFF + it * 256 + wr * 64 + quad * 16);
    }
    compute(A, hv, it);

    // My ds_reads of buf bf retired; barrier -> everyone's are.
    asm volatile("s_waitcnt lgkmcnt(0)" ::: "memory");
    __builtin_amdgcn_sched_barrier(0);
    __builtin_amdgcn_s_barrier();              // buf bf safe to overwrite
    __builtin_amdgcn_sched_barrier(0);
    stage((it + RB) & (NCH - 1), bf);          // tail wrap: redundant, never read
    bf = (bf == RB - 1) ? 0 : bf + 1;
  }

  // Drain in-flight DMAs, then all waves quiesce before aliasing LDS.
  asm volatile("s_waitcnt vmcnt(0)" ::: "memory");
  __syncthreads();

  float (*c_s1)[MT] = (float (*)[MT])(smem);              // 8 KB
  float (*c_s2)[MT] = (float (*)[MT])(smem + 8192);       // 8 KB
  int   (*c_i1)[MT] = (int (*)[MT])(smem + 16384);        // 8 KB
  int   (*c_i2)[MT] = (int (*)[MT])(smem + 24576);        // 8 KB
  int*   widx       = (int*)(smem + 32768);               // 512 B

  // ---- surface per-cell top-2 (cell = wr*4+quad; per token-half:
  // 16 cells x 512 codes; waves tg=0/1 write disjoint m ranges) ----
  {
    const int cell = wr * 4 + quad;
#pragma unroll
    for (int s = 0; s < NSETS; ++s) {
      const int m = tg * 64 + s * 16 + col;
      const unsigned K1 = m1[s], K2 = m2[s];
      c_s1[cell][m] = __uint_as_float(K1 & ~511u);
      c_s2[cell][m] = __uint_as_float(K2 & ~511u);
      // decode: local = it*4 + r -> code = it*64 + wr*16 + quad*4 + r
      c_i1[cell][m] = (int)((K1 & 511u) >> 2) * KC + wr * 16 + quad * 4 + (int)(K1 & 3u);
      c_i2[cell][m] = (int)((K2 & 511u) >> 2) * KC + wr * 16 + quad * 4 + (int)(K2 & 3u);
    }
  }
  __syncthreads();

  // ---- phase 2: fast path or numpy-faithful refine (2 waves, 1 token/lane) ----
  if (tid < MT) {
#pragma clang fp contract(off)   // numpy: separate mul then add; no FMA
    const int m = tid;

    float smin = FLT_MAX; int fidx = 0x7fffffff;
    for (int c = 0; c < NCELL; ++c) {
      const float a = c_s1[c][m];
      if (a < smin) { smin = a; fidx = c_i1[c][m]; }
    }
    const float lim = smin + 8e-3f;   // covers 2*e_screen(2.8e-3) + key floor
                                      // 2.4e-4 + numpy noise, ~1.4x slack
    int cnt = 0;
    for (int c = 0; c < NCELL; ++c) {
      cnt += (c_s1[c][m] <= lim);
      cnt += (c_s2[c][m] <= lim);
    }

    int besti;
    if (cnt == 1) {
      besti = fidx;   // unique in-margin candidate: approx argmin == numpy argmin
    } else {
      const float* xz = zb + m;
      float xm[DDIM];
      for (int d = 0; d < DDIM; ++d) xm[d] = xz[(size_t)d * 4096];

      float r[8];
      for (int j = 0; j < 8; ++j) r[j] = xm[j] * xm[j];
      for (int i = 8; i < DDIM; i += 8)
        for (int j = 0; j < 8; ++j) r[j] += xm[i + j] * xm[i + j];
      const float S = ((r[0] + r[1]) + (r[2] + r[3])) + ((r[4] + r[5]) + (r[6] + r[7]));

      float bestD = FLT_MAX;
      besti = 0x7fffffff;
      for (int c = 0; c < NCELL; ++c) {
        for (int h = 0; h < 2; ++h) {
          const float sp = h ? c_s2[c][m] : c_s1[c][m];
          if (sp > lim) continue;
          const int idx = h ? c_i2[c][m] : c_i1[c][m];
          const float* crow = cb + (size_t)idx * DDIM;

          float rn[8];
          for (int j = 0; j < 8; ++j) rn[j] = crow[j] * crow[j];
          for (int i = 8; i < DDIM; i += 8)
            for (int j = 0; j < 8; ++j) rn[j] += crow[i + j] * crow[i + j];
          const float Nk =
              ((rn[0] + rn[1]) + (rn[2] + rn[3])) + ((rn[4] + rn[5]) + (rn[6] + rn[7]));

          double p64 = 0.0;
          for (int d = 0; d < DDIM; ++d) p64 += (double)xm[d] * (double)crow[d];
          const float pf = (float)p64;

          const float twop = 2.0f * pf;
          const float t1   = S - twop;
          const float Dv   = t1 + Nk;
          if (Dv < bestD || (Dv == bestD && idx < besti)) { bestD = Dv; besti = idx; }
        }
      }
    }
    widx[m] = besti;
  }
  __syncthreads();

  // ---- gather winners, write z_q (128-lane coalesced rows; cb L2-hot) ----
  {
    const int m = tid & 127, dg = tid >> 7;    // dg 0..3
    const int wi = widx[m];
    const float* crow = cb + (size_t)wi * DDIM;
    float* ob = out + (size_t)bb * (DDIM * 4096) + hw0;
#pragma unroll
    for (int p = 0; p < 16; ++p) {
      const int d = dg * 16 + p;
      ob[(size_t)d * 4096 + m] = crow[d];
    }
  }
}

extern "C" void kernel_launch(void* const* d_in, const int* in_sizes, int n_in,
                              void* d_out, int out_size, void* d_ws, size_t ws_size,
                              hipStream_t stream) {
  const float* ze = (const float*)d_in[0];    // [8,64,64,64]
  const float* cb = (const float*)d_in[1];    // [8192,64]
  float* hn = (float*)d_ws;                                     // 32 KB
  unsigned short* wcb = (unsigned short*)((char*)d_ws + 32768); // 1 MB frag-linear hi
  float* out = (float*)d_out;

  prep_kernel<<<256, 128, 0, stream>>>(cb, wcb, hn);
  vq_kernel<<<NTOK / MT, 512, 0, stream>>>(ze, cb, hn, wcb, out);
}